// Round 1
// baseline (709.000 us; speedup 1.0000x reference)
//
#include <hip/hip_runtime.h>

#define B_ 4
#define SQ_ 2048
#define SKV_ 2048
#define E_ 1024
#define H_ 16
#define D_ 64

typedef __bf16 bf16x8 __attribute__((ext_vector_type(8)));
typedef float f32x4 __attribute__((ext_vector_type(4)));

__device__ inline f32x4 zero4() { f32x4 z = {0.f, 0.f, 0.f, 0.f}; return z; }

// Convert 8 consecutive f32 (32B-aligned) to a bf16x8 MFMA fragment.
__device__ inline bf16x8 cvt8(const float* __restrict__ p) {
    const float4 a = ((const float4*)p)[0];
    const float4 b = ((const float4*)p)[1];
    bf16x8 r;
    r[0] = (__bf16)a.x; r[1] = (__bf16)a.y; r[2] = (__bf16)a.z; r[3] = (__bf16)a.w;
    r[4] = (__bf16)b.x; r[5] = (__bf16)b.y; r[6] = (__bf16)b.z; r[7] = (__bf16)b.w;
    return r;
}

#define MFMA16(a, b, c) __builtin_amdgcn_mfma_f32_16x16x32_bf16(a, b, c, 0, 0, 0)

// ---------------------------------------------------------------------------
// wo f32 [E][E] -> bf16 same layout (row n, col k — already B-operand friendly)
__global__ __launch_bounds__(256) void cast_wo_kernel(const float* __restrict__ wo,
                                                      __bf16* __restrict__ wo_bf) {
    int i = (blockIdx.x * 256 + threadIdx.x) * 4;
    float4 v = *(const float4*)(wo + i);
    wo_bf[i + 0] = (__bf16)v.x;
    wo_bf[i + 1] = (__bf16)v.y;
    wo_bf[i + 2] = (__bf16)v.z;
    wo_bf[i + 3] = (__bf16)v.w;
}

// ---------------------------------------------------------------------------
// Q projection: qh[b,h,s,e] = sum_d q[b,s,h*64+d] * wq[h,e,d] + bq[h,e]
// Block: 256 thr = 4 waves; block tile 64 s-rows; wave tile 16 s-rows x 64 cols.
__global__ __launch_bounds__(256) void proj_q_kernel(const float* __restrict__ q,
                                                     const float* __restrict__ wq,
                                                     const float* __restrict__ bq,
                                                     __bf16* __restrict__ qh) {
    const int w = threadIdx.x >> 6, lane = threadIdx.x & 63;
    const int l15 = lane & 15, quad = lane >> 4;
    const int b = blockIdx.z, h = blockIdx.y;
    const int s_base = blockIdx.x * 64 + w * 16;

    const float* qrow = q + ((size_t)b * SQ_ + s_base + l15) * E_ + h * D_ + quad * 8;
    bf16x8 a0 = cvt8(qrow);
    bf16x8 a1 = cvt8(qrow + 32);

    f32x4 acc[4] = {zero4(), zero4(), zero4(), zero4()};
#pragma unroll
    for (int nb = 0; nb < 4; ++nb) {
        const float* wrow = wq + (size_t)h * D_ * D_ + (nb * 16 + l15) * D_ + quad * 8;
        bf16x8 b0 = cvt8(wrow);
        bf16x8 b1 = cvt8(wrow + 32);
        acc[nb] = MFMA16(a0, b0, acc[nb]);
        acc[nb] = MFMA16(a1, b1, acc[nb]);
    }

    __bf16* obase = qh + ((size_t)(b * H_ + h) * SQ_ + s_base) * D_;
#pragma unroll
    for (int nb = 0; nb < 4; ++nb) {
        const int col = nb * 16 + l15;
        const float bias = bq[h * D_ + col];
#pragma unroll
        for (int r = 0; r < 4; ++r) {
            obase[(quad * 4 + r) * D_ + col] = (__bf16)(acc[nb][r] + bias);
        }
    }
}

// ---------------------------------------------------------------------------
// KV projection: kh[b,h,t,e] row-major [B,H,SKV,D]; vh stored TRANSPOSED
// vh_t[b,h,d,t] so PV B-fragments load contiguous 16B.
__global__ __launch_bounds__(256) void proj_kv_kernel(const float* __restrict__ kv,
                                                      const float* __restrict__ wk,
                                                      const float* __restrict__ bk,
                                                      const float* __restrict__ wv,
                                                      const float* __restrict__ bv,
                                                      __bf16* __restrict__ kh,
                                                      __bf16* __restrict__ vh_t) {
    const int w = threadIdx.x >> 6, lane = threadIdx.x & 63;
    const int l15 = lane & 15, quad = lane >> 4;
    const int b = blockIdx.z, h = blockIdx.y;
    const int t_base = blockIdx.x * 64 + w * 16;

    const float* xrow = kv + ((size_t)b * SKV_ + t_base + l15) * E_ + h * D_ + quad * 8;
    bf16x8 a0 = cvt8(xrow);
    bf16x8 a1 = cvt8(xrow + 32);

    f32x4 acck[4] = {zero4(), zero4(), zero4(), zero4()};
    f32x4 accv[4] = {zero4(), zero4(), zero4(), zero4()};
#pragma unroll
    for (int nb = 0; nb < 4; ++nb) {
        const float* wkrow = wk + (size_t)h * D_ * D_ + (nb * 16 + l15) * D_ + quad * 8;
        const float* wvrow = wv + (size_t)h * D_ * D_ + (nb * 16 + l15) * D_ + quad * 8;
        bf16x8 bk0 = cvt8(wkrow);
        bf16x8 bk1 = cvt8(wkrow + 32);
        bf16x8 bv0 = cvt8(wvrow);
        bf16x8 bv1 = cvt8(wvrow + 32);
        acck[nb] = MFMA16(a0, bk0, acck[nb]);
        acck[nb] = MFMA16(a1, bk1, acck[nb]);
        accv[nb] = MFMA16(a0, bv0, accv[nb]);
        accv[nb] = MFMA16(a1, bv1, accv[nb]);
    }

    __bf16* kbase = kh + ((size_t)(b * H_ + h) * SKV_ + t_base) * D_;
    __bf16* vbase = vh_t + (size_t)(b * H_ + h) * D_ * SKV_;
#pragma unroll
    for (int nb = 0; nb < 4; ++nb) {
        const int col = nb * 16 + l15;
        const float biask = bk[h * D_ + col];
        const float biasv = bv[h * D_ + col];
#pragma unroll
        for (int r = 0; r < 4; ++r) {
            const int row = quad * 4 + r;  // t within tile
            kbase[row * D_ + col] = (__bf16)(acck[nb][r] + biask);
            vbase[(size_t)col * SKV_ + t_base + row] = (__bf16)(accv[nb][r] + biasv);
        }
    }
}

// ---------------------------------------------------------------------------
// Flash attention. Block: 64 q-rows (4 waves x 16), kv-tile 64, online softmax.
// qh [B,H,SQ,D], kh [B,H,SKV,D], vh_t [B,H,D,SKV] -> ctx bf16 [B,SQ,E]
__global__ __launch_bounds__(256) void attn_kernel(const __bf16* __restrict__ qh,
                                                   const __bf16* __restrict__ kh,
                                                   const __bf16* __restrict__ vh_t,
                                                   __bf16* __restrict__ ctx) {
    // P round-trip: C-layout -> A-operand layout. Row stride 72 bf16 = 144B:
    // 16B aligned, and b128 reads land 2 lanes/bank (free) instead of 16-way.
    __shared__ __bf16 p_lds[4][16][72];

    const int w = threadIdx.x >> 6, lane = threadIdx.x & 63;
    const int l15 = lane & 15, quad = lane >> 4;
    const int b = blockIdx.z, h = blockIdx.y;
    const int bh = b * H_ + h;
    const int s_base = blockIdx.x * 64 + w * 16;

    const __bf16* qbase = qh + ((size_t)bh * SQ_ + s_base + l15) * D_ + quad * 8;
    bf16x8 aq0 = *(const bf16x8*)qbase;
    bf16x8 aq1 = *(const bf16x8*)(qbase + 32);

    f32x4 o[4] = {zero4(), zero4(), zero4(), zero4()};
    float m_r[4], l_r[4];
#pragma unroll
    for (int r = 0; r < 4; ++r) { m_r[r] = -3.0e38f; l_r[r] = 0.f; }

    const __bf16* kbase = kh + (size_t)bh * SKV_ * D_;
    const __bf16* vbase = vh_t + (size_t)bh * D_ * SKV_;

    for (int t0 = 0; t0 < SKV_; t0 += 64) {
        // S = Q K^T for this 16x64 tile (per wave)
        f32x4 s[4] = {zero4(), zero4(), zero4(), zero4()};
#pragma unroll
        for (int nb = 0; nb < 4; ++nb) {
            const __bf16* kr = kbase + (size_t)(t0 + nb * 16 + l15) * D_ + quad * 8;
            bf16x8 bk0 = *(const bf16x8*)kr;
            bf16x8 bk1 = *(const bf16x8*)(kr + 32);
            s[nb] = MFMA16(aq0, bk0, s[nb]);
            s[nb] = MFMA16(aq1, bk1, s[nb]);
        }
        // online softmax, per C-layout row r (row = quad*4+r)
#pragma unroll
        for (int r = 0; r < 4; ++r) {
            float v0 = s[0][r] * 0.125f, v1 = s[1][r] * 0.125f;
            float v2 = s[2][r] * 0.125f, v3 = s[3][r] * 0.125f;
            float mx = fmaxf(fmaxf(v0, v1), fmaxf(v2, v3));
            mx = fmaxf(mx, __shfl_xor(mx, 1));
            mx = fmaxf(mx, __shfl_xor(mx, 2));
            mx = fmaxf(mx, __shfl_xor(mx, 4));
            mx = fmaxf(mx, __shfl_xor(mx, 8));
            const float m_new = fmaxf(m_r[r], mx);
            const float alpha = __expf(m_r[r] - m_new);
            m_r[r] = m_new;
            const float p0 = __expf(v0 - m_new), p1 = __expf(v1 - m_new);
            const float p2 = __expf(v2 - m_new), p3 = __expf(v3 - m_new);
            float rs = p0 + p1 + p2 + p3;
            rs += __shfl_xor(rs, 1);
            rs += __shfl_xor(rs, 2);
            rs += __shfl_xor(rs, 4);
            rs += __shfl_xor(rs, 8);
            l_r[r] = l_r[r] * alpha + rs;
            o[0][r] *= alpha; o[1][r] *= alpha; o[2][r] *= alpha; o[3][r] *= alpha;
            const int row = quad * 4 + r;
            p_lds[w][row][0 * 16 + l15] = (__bf16)p0;
            p_lds[w][row][1 * 16 + l15] = (__bf16)p1;
            p_lds[w][row][2 * 16 + l15] = (__bf16)p2;
            p_lds[w][row][3 * 16 + l15] = (__bf16)p3;
        }
        // O += P V  (P from LDS in A-operand layout; V^T fragments contiguous)
#pragma unroll
        for (int ks = 0; ks < 2; ++ks) {
            bf16x8 ap = *(const bf16x8*)&p_lds[w][l15][ks * 32 + quad * 8];
#pragma unroll
            for (int nb = 0; nb < 4; ++nb) {
                const __bf16* vr = vbase + (size_t)(nb * 16 + l15) * SKV_ + t0 + ks * 32 + quad * 8;
                bf16x8 bv = *(const bf16x8*)vr;
                o[nb] = MFMA16(ap, bv, o[nb]);
            }
        }
    }

    __bf16* cbase = ctx + ((size_t)b * SQ_ + s_base) * E_ + h * D_;
#pragma unroll
    for (int r = 0; r < 4; ++r) {
        const float inv = 1.f / l_r[r];
        const int row = quad * 4 + r;
#pragma unroll
        for (int nb = 0; nb < 4; ++nb) {
            cbase[row * E_ + nb * 16 + l15] = (__bf16)(o[nb][r] * inv);
        }
    }
}

// ---------------------------------------------------------------------------
// Output GEMM: out[m,n] = sum_k ctx[m,k] * wo[n,k] + bo[n]
// M=8192, N=1024, K=1024. Block tile 128x64 (4 waves x 32 rows).
__global__ __launch_bounds__(256) void ogemm_kernel(const __bf16* __restrict__ ctx,
                                                    const __bf16* __restrict__ wo_bf,
                                                    const float* __restrict__ bo,
                                                    float* __restrict__ out) {
    const int w = threadIdx.x >> 6, lane = threadIdx.x & 63;
    const int l15 = lane & 15, quad = lane >> 4;
    const int m_base = blockIdx.x * 128 + w * 32;
    const int n_base = blockIdx.y * 64;

    f32x4 acc[2][4] = {{zero4(), zero4(), zero4(), zero4()},
                       {zero4(), zero4(), zero4(), zero4()}};

    const __bf16* arow0 = ctx + (size_t)(m_base + l15) * E_ + quad * 8;
    const __bf16* arow1 = arow0 + (size_t)16 * E_;
    const __bf16* brow = wo_bf + (size_t)(n_base + l15) * E_ + quad * 8;

    for (int k0 = 0; k0 < E_; k0 += 32) {
        bf16x8 a0 = *(const bf16x8*)(arow0 + k0);
        bf16x8 a1 = *(const bf16x8*)(arow1 + k0);
#pragma unroll
        for (int nb = 0; nb < 4; ++nb) {
            bf16x8 bf = *(const bf16x8*)(brow + (size_t)nb * 16 * E_ + k0);
            acc[0][nb] = MFMA16(a0, bf, acc[0][nb]);
            acc[1][nb] = MFMA16(a1, bf, acc[1][nb]);
        }
    }

#pragma unroll
    for (int sub = 0; sub < 2; ++sub) {
#pragma unroll
        for (int nb = 0; nb < 4; ++nb) {
            const int col = n_base + nb * 16 + l15;
            const float bias = bo[col];
#pragma unroll
            for (int r = 0; r < 4; ++r) {
                const int row = m_base + sub * 16 + quad * 4 + r;
                out[(size_t)row * E_ + col] = acc[sub][nb][r] + bias;
            }
        }
    }
}

// ---------------------------------------------------------------------------
extern "C" void kernel_launch(void* const* d_in, const int* in_sizes, int n_in,
                              void* d_out, int out_size, void* d_ws, size_t ws_size,
                              hipStream_t stream) {
    const float* query = (const float*)d_in[0];
    const float* key_value = (const float*)d_in[1];
    const float* wq = (const float*)d_in[2];
    const float* bq = (const float*)d_in[3];
    const float* wk = (const float*)d_in[4];
    const float* bk = (const float*)d_in[5];
    const float* wv = (const float*)d_in[6];
    const float* bv = (const float*)d_in[7];
    const float* wo = (const float*)d_in[8];
    const float* bo = (const float*)d_in[9];
    float* out = (float*)d_out;

    // workspace layout (needs 66 MB): qh | kh | vh_t | ctx | wo_bf
    char* ws = (char*)d_ws;
    __bf16* qh = (__bf16*)(ws);                         // 16 MB [B,H,SQ,D]
    __bf16* kh = (__bf16*)(ws + (16u << 20));           // 16 MB [B,H,SKV,D]
    __bf16* vh_t = (__bf16*)(ws + (32u << 20));         // 16 MB [B,H,D,SKV]
    __bf16* ctxb = (__bf16*)(ws + (48u << 20));         // 16 MB [B,SQ,E]
    __bf16* wo_bf = (__bf16*)(ws + (64u << 20));        // 2 MB  [E,E]

    hipLaunchKernelGGL(cast_wo_kernel, dim3(E_ * E_ / 1024), dim3(256), 0, stream, wo, wo_bf);
    hipLaunchKernelGGL(proj_q_kernel, dim3(SQ_ / 64, H_, B_), dim3(256), 0, stream,
                       query, wq, bq, qh);
    hipLaunchKernelGGL(proj_kv_kernel, dim3(SKV_ / 64, H_, B_), dim3(256), 0, stream,
                       key_value, wk, bk, wv, bv, kh, vh_t);
    hipLaunchKernelGGL(attn_kernel, dim3(SQ_ / 64, H_, B_), dim3(256), 0, stream,
                       qh, kh, vh_t, ctxb);
    hipLaunchKernelGGL(ogemm_kernel, dim3(B_ * SQ_ / 128, E_ / 64), dim3(256), 0, stream,
                       ctxb, wo_bf, bo, out);
}